// Round 1
// baseline (329.532 us; speedup 1.0000x reference)
//
#include <hip/hip_runtime.h>

// NMS3D on x: (B=4, CH=4, D=32, H=256, W=256) fp32.
// out = x where x is a strict 26-neighbor local max in the (d,h,w) interior, else 0.
// Strategy: 1 thread per 4 consecutive w elements (float4). For each of the 9
// (dz,dy) rows load 1 aligned float4 + 2 guarded edge scalars; per-lane neighbor
// max in registers; write masked float4. Memory-bound; cache serves the 9x
// spatial reuse (input 128 MiB < 256 MiB L3).

constexpr int W = 256;
constexpr int H = 256;
constexpr int D = 32;
constexpr int SH = W;        // h stride
constexpr int SD = W * H;    // d stride (65536)

__global__ __launch_bounds__(256) void nms3d_kernel(const float* __restrict__ x,
                                                    float* __restrict__ out,
                                                    int n4) {
    int t = blockIdx.x * blockDim.x + threadIdx.x;
    if (t >= n4) return;
    int i0 = t << 2;                    // linear index of first of 4 elements
    int w0 = i0 & (W - 1);              // 0,4,...,252
    int h  = (i0 >> 8) & (H - 1);
    int d  = (i0 >> 16) & (D - 1);

    const float4 c = *(const float4*)(x + i0);

    // d/h boundary: entire vector is outside the interior -> zeros.
    if (d == 0 || d == D - 1 || h == 0 || h == H - 1) {
        *(float4*)(out + i0) = make_float4(0.f, 0.f, 0.f, 0.f);
        return;
    }

    const bool has_left  = (w0 > 0);        // lane 0 is interior in w
    const bool has_right = (w0 + 4 < W);    // lane 3 is interior in w

    float nmax0 = -INFINITY, nmax1 = -INFINITY, nmax2 = -INFINITY, nmax3 = -INFINITY;

    #pragma unroll
    for (int dz = -1; dz <= 1; ++dz) {
        #pragma unroll
        for (int dy = -1; dy <= 1; ++dy) {
            const float* row = x + i0 + dz * SD + dy * SH;
            const bool is_center = (dz == 0) && (dy == 0);
            float4 v = is_center ? c : *(const float4*)row;
            float vm1 = has_left  ? row[-1] : -INFINITY;  // lane 0 masked when absent
            float v4  = has_right ? row[4]  : -INFINITY;  // lane 3 masked when absent
            if (is_center) {
                // center row contributes only left/right neighbors
                nmax0 = fmaxf(nmax0, fmaxf(vm1, v.y));
                nmax1 = fmaxf(nmax1, fmaxf(v.x, v.z));
                nmax2 = fmaxf(nmax2, fmaxf(v.y, v.w));
                nmax3 = fmaxf(nmax3, fmaxf(v.z, v4));
            } else {
                nmax0 = fmaxf(nmax0, fmaxf(fmaxf(vm1, v.x), v.y));
                nmax1 = fmaxf(nmax1, fmaxf(fmaxf(v.x, v.y), v.z));
                nmax2 = fmaxf(nmax2, fmaxf(fmaxf(v.y, v.z), v.w));
                nmax3 = fmaxf(nmax3, fmaxf(fmaxf(v.z, v.w), v4));
            }
        }
    }

    float4 o;
    o.x = (has_left  && c.x > nmax0) ? c.x : 0.f;
    o.y = (c.y > nmax1) ? c.y : 0.f;
    o.z = (c.z > nmax2) ? c.z : 0.f;
    o.w = (has_right && c.w > nmax3) ? c.w : 0.f;
    *(float4*)(out + i0) = o;
}

extern "C" void kernel_launch(void* const* d_in, const int* in_sizes, int n_in,
                              void* d_out, int out_size, void* d_ws, size_t ws_size,
                              hipStream_t stream) {
    const float* x = (const float*)d_in[0];
    float* out = (float*)d_out;
    int n4 = out_size >> 2;  // 8,388,608 float4 groups
    int block = 256;
    int grid = (n4 + block - 1) / block;
    nms3d_kernel<<<grid, block, 0, stream>>>(x, out, n4);
}

// Round 2
// 242.442 us; speedup vs baseline: 1.3592x; 1.3592x over previous
//
#include <hip/hip_runtime.h>

// NMS3D on x: (B=4, CH=4, D=32, H=256, W=256) fp32, strict 26-neighbor max.
// R1: h-rolling register window + wave shuffles for w-edges.
//   - One wave64 covers one full W row (64 lanes x float4). Edge neighbors
//     (w0-1, w0+4) come from adjacent lanes via __shfl (LDS pipe), eliminating
//     the 18 scalar VMEM loads/group that made R0 L1-tag-bound.
//   - Each wave owns a 16-row h-strip at fixed (b,ch,d): rolls a 3(dz) x 3(h)
//     float4 window in registers; per h-step only 3 new float4 loads + 1 store.
// VMEM instrs/chunk: 448 -> ~70. Expect HBM-floor-bound (~37-45 us ideal).

constexpr int W  = 256;
constexpr int H  = 256;
constexpr int D  = 32;
constexpr int SH = W;         // h stride
constexpr int SD = W * H;     // d stride
constexpr int HC = 16;        // h rows per wave chunk
constexpr int HCHUNKS = H / HC;
constexpr int BC = 16;        // B*CH

__global__ __launch_bounds__(256) void nms3d_kernel(const float* __restrict__ x,
                                                    float* __restrict__ out) {
    const int wid  = (blockIdx.x << 2) | (threadIdx.x >> 6);
    const int lane = threadIdx.x & 63;
    const int hc   = wid & (HCHUNKS - 1);
    const int d    = (wid >> 4) & (D - 1);          // HCHUNKS=16
    const int bc   = wid >> 9;                      // / (HCHUNKS*D)
    const int col  = bc * (D * SD) + d * SD + (lane << 2);  // index of (h=0, w0)
    const int h0   = hc * HC;

    const float4 zero = make_float4(0.f, 0.f, 0.f, 0.f);

    if (d == 0 || d == D - 1) {
        // whole chunk is d-boundary: zeros
        #pragma unroll
        for (int h = 0; h < HC; ++h)
            *(float4*)(out + col + (h0 + h) * SH) = zero;
        return;
    }

    const int h_begin = (h0 == 0) ? 1 : h0;
    const int h_end   = (h0 + HC == H) ? (H - 2) : (h0 + HC - 1);
    if (h0 == 0)      *(float4*)(out + col) = zero;                  // h = 0
    if (h0 + HC == H) *(float4*)(out + col + (H - 1) * SH) = zero;   // h = H-1

    // rolling window: v[dz][s], s=0:h-1, 1:h, 2:h+1; edge scalars via shuffle
    float4 v[3][3];
    float  lm[3][3], rp[3][3];

    #pragma unroll
    for (int s = 0; s < 2; ++s) {
        const int h = h_begin - 1 + s;
        #pragma unroll
        for (int dz = 0; dz < 3; ++dz) {
            float4 t = *(const float4*)(x + col + (dz - 1) * SD + h * SH);
            v[dz][s]  = t;
            lm[dz][s] = __shfl_up(t.w, 1);    // value at w0-1 (lane0: garbage, masked)
            rp[dz][s] = __shfl_down(t.x, 1);  // value at w0+4 (lane63: garbage, masked)
        }
    }

    for (int h = h_begin; h <= h_end; ++h) {
        // load slot 2 = rows at h+1
        #pragma unroll
        for (int dz = 0; dz < 3; ++dz) {
            float4 t = *(const float4*)(x + col + (dz - 1) * SD + (h + 1) * SH);
            v[dz][2]  = t;
            lm[dz][2] = __shfl_up(t.w, 1);
            rp[dz][2] = __shfl_down(t.x, 1);
        }

        const float4 c = v[1][1];
        float n0 = -INFINITY, n1 = -INFINITY, n2 = -INFINITY, n3 = -INFINITY;

        #pragma unroll
        for (int dz = 0; dz < 3; ++dz) {
            #pragma unroll
            for (int s = 0; s < 3; ++s) {
                const float4 r = v[dz][s];
                const float  l = lm[dz][s];
                const float  q = rp[dz][s];
                if (dz == 1 && s == 1) {
                    // center row: only left/right neighbors
                    n0 = fmaxf(n0, fmaxf(l,   r.y));
                    n1 = fmaxf(n1, fmaxf(r.x, r.z));
                    n2 = fmaxf(n2, fmaxf(r.y, r.w));
                    n3 = fmaxf(n3, fmaxf(r.z, q));
                } else {
                    n0 = fmaxf(n0, fmaxf(fmaxf(l,   r.x), r.y));
                    n1 = fmaxf(n1, fmaxf(fmaxf(r.x, r.y), r.z));
                    n2 = fmaxf(n2, fmaxf(fmaxf(r.y, r.z), r.w));
                    n3 = fmaxf(n3, fmaxf(fmaxf(r.z, r.w), q));
                }
            }
        }

        float4 o;
        o.x = (lane > 0  && c.x > n0) ? c.x : 0.f;
        o.y = (c.y > n1) ? c.y : 0.f;
        o.z = (c.z > n2) ? c.z : 0.f;
        o.w = (lane < 63 && c.w > n3) ? c.w : 0.f;
        *(float4*)(out + col + h * SH) = o;

        // shift window
        #pragma unroll
        for (int dz = 0; dz < 3; ++dz) {
            v[dz][0]  = v[dz][1];  v[dz][1]  = v[dz][2];
            lm[dz][0] = lm[dz][1]; lm[dz][1] = lm[dz][2];
            rp[dz][0] = rp[dz][1]; rp[dz][1] = rp[dz][2];
        }
    }
}

extern "C" void kernel_launch(void* const* d_in, const int* in_sizes, int n_in,
                              void* d_out, int out_size, void* d_ws, size_t ws_size,
                              hipStream_t stream) {
    const float* x = (const float*)d_in[0];
    float* out = (float*)d_out;
    // total waves = BC * D * HCHUNKS = 16*32*16 = 8192; 4 waves/block
    const int grid = (BC * D * HCHUNKS) / 4;   // 2048 blocks
    nms3d_kernel<<<grid, 256, 0, stream>>>(x, out);
}

// Round 3
// 235.020 us; speedup vs baseline: 1.4021x; 1.0316x over previous
//
#include <hip/hip_runtime.h>

// NMS3D (4,4,32,256,256) fp32, strict 26-neighbor max.
// R2: R1 + one-step software prefetch (rows h+2 loaded during compute of h),
//     HC=8 (16384 waves for backfill), nontemporal float4 stores.
// One wave64 = one W row (64 lanes x float4); w-edges via __shfl; h-rolling
// 3(dz) x 3(h) register window.

typedef float v4f __attribute__((ext_vector_type(4)));

constexpr int W  = 256;
constexpr int H  = 256;
constexpr int D  = 32;
constexpr int SH = W;
constexpr int SD = W * H;
constexpr int HC = 8;                 // h rows per wave chunk
constexpr int HCHUNKS = H / HC;       // 32
constexpr int BC = 16;                // B*CH

__global__ __launch_bounds__(256) void nms3d_kernel(const float* __restrict__ x,
                                                    float* __restrict__ out) {
    const int wid  = (blockIdx.x << 2) | (threadIdx.x >> 6);
    const int lane = threadIdx.x & 63;
    const int hc   = wid & (HCHUNKS - 1);
    const int d    = (wid >> 5) & (D - 1);
    const int bc   = wid >> 10;
    const int col  = bc * (D * SD) + d * SD + (lane << 2);
    const int h0   = hc * HC;

    const v4f zero = (v4f){0.f, 0.f, 0.f, 0.f};

    if (d == 0 || d == D - 1) {
        #pragma unroll
        for (int h = 0; h < HC; ++h)
            __builtin_nontemporal_store(zero, (v4f*)(out + col + (h0 + h) * SH));
        return;
    }

    const int h_begin = (h0 == 0) ? 1 : h0;
    const int h_end   = (h0 + HC == H) ? (H - 2) : (h0 + HC - 1);
    if (h0 == 0)      __builtin_nontemporal_store(zero, (v4f*)(out + col));
    if (h0 + HC == H) __builtin_nontemporal_store(zero, (v4f*)(out + col + (H - 1) * SH));

    // window: s0 = rows h-1, s1 = rows h; pf = rows h+1 in flight
    v4f s0[3], s1[3], pf[3];
    float lm0[3], rp0[3], lm1[3], rp1[3];

    #pragma unroll
    for (int dz = 0; dz < 3; ++dz) {
        const float* base = x + col + (dz - 1) * SD;
        v4f a = *(const v4f*)(base + (h_begin - 1) * SH);
        v4f b = *(const v4f*)(base + h_begin * SH);
        pf[dz] = *(const v4f*)(base + (h_begin + 1) * SH);
        s0[dz] = a; lm0[dz] = __shfl_up(a.w, 1); rp0[dz] = __shfl_down(a.x, 1);
        s1[dz] = b; lm1[dz] = __shfl_up(b.w, 1); rp1[dz] = __shfl_down(b.x, 1);
    }

    for (int h = h_begin; h <= h_end; ++h) {
        // consume prefetch -> slot 2 (waitcnt lands here)
        v4f s2[3]; float lm2[3], rp2[3];
        #pragma unroll
        for (int dz = 0; dz < 3; ++dz) {
            v4f t = pf[dz];
            s2[dz] = t;
            lm2[dz] = __shfl_up(t.w, 1);
            rp2[dz] = __shfl_down(t.x, 1);
        }

        // issue next prefetch (rows h+2, clamped; consumed next iteration)
        int hp = h + 2; if (hp > H - 1) hp = H - 1;
        #pragma unroll
        for (int dz = 0; dz < 3; ++dz)
            pf[dz] = *(const v4f*)(x + col + (dz - 1) * SD + hp * SH);

        const v4f c = s1[1];
        float n0 = -INFINITY, n1 = -INFINITY, n2 = -INFINITY, n3 = -INFINITY;

        #pragma unroll
        for (int dz = 0; dz < 3; ++dz) {
            // row h-1
            {
                const v4f r = s0[dz]; const float l = lm0[dz], q = rp0[dz];
                n0 = fmaxf(n0, fmaxf(fmaxf(l, r.x), r.y));
                n1 = fmaxf(n1, fmaxf(fmaxf(r.x, r.y), r.z));
                n2 = fmaxf(n2, fmaxf(fmaxf(r.y, r.z), r.w));
                n3 = fmaxf(n3, fmaxf(fmaxf(r.z, r.w), q));
            }
            // row h
            if (dz == 1) {
                const v4f r = s1[1]; const float l = lm1[1], q = rp1[1];
                n0 = fmaxf(n0, fmaxf(l, r.y));
                n1 = fmaxf(n1, fmaxf(r.x, r.z));
                n2 = fmaxf(n2, fmaxf(r.y, r.w));
                n3 = fmaxf(n3, fmaxf(r.z, q));
            } else {
                const v4f r = s1[dz]; const float l = lm1[dz], q = rp1[dz];
                n0 = fmaxf(n0, fmaxf(fmaxf(l, r.x), r.y));
                n1 = fmaxf(n1, fmaxf(fmaxf(r.x, r.y), r.z));
                n2 = fmaxf(n2, fmaxf(fmaxf(r.y, r.z), r.w));
                n3 = fmaxf(n3, fmaxf(fmaxf(r.z, r.w), q));
            }
            // row h+1
            {
                const v4f r = s2[dz]; const float l = lm2[dz], q = rp2[dz];
                n0 = fmaxf(n0, fmaxf(fmaxf(l, r.x), r.y));
                n1 = fmaxf(n1, fmaxf(fmaxf(r.x, r.y), r.z));
                n2 = fmaxf(n2, fmaxf(fmaxf(r.y, r.z), r.w));
                n3 = fmaxf(n3, fmaxf(fmaxf(r.z, r.w), q));
            }
        }

        v4f o;
        o.x = (lane > 0  && c.x > n0) ? c.x : 0.f;
        o.y = (c.y > n1) ? c.y : 0.f;
        o.z = (c.z > n2) ? c.z : 0.f;
        o.w = (lane < 63 && c.w > n3) ? c.w : 0.f;
        __builtin_nontemporal_store(o, (v4f*)(out + col + h * SH));

        // shift window
        #pragma unroll
        for (int dz = 0; dz < 3; ++dz) {
            s0[dz] = s1[dz]; lm0[dz] = lm1[dz]; rp0[dz] = rp1[dz];
            s1[dz] = s2[dz]; lm1[dz] = lm2[dz]; rp1[dz] = rp2[dz];
        }
    }
}

extern "C" void kernel_launch(void* const* d_in, const int* in_sizes, int n_in,
                              void* d_out, int out_size, void* d_ws, size_t ws_size,
                              hipStream_t stream) {
    const float* x = (const float*)d_in[0];
    float* out = (float*)d_out;
    // waves = BC * D * HCHUNKS = 16*32*32 = 16384; 4 waves/block -> 4096 blocks
    const int grid = (BC * D * HCHUNKS) / 4;
    nms3d_kernel<<<grid, 256, 0, stream>>>(x, out);
}